// Round 5
// baseline (1456.377 us; speedup 1.0000x reference)
//
#include <hip/hip_runtime.h>
#include <hip/hip_fp16.h>

typedef __bf16 bf16x8 __attribute__((ext_vector_type(8)));
typedef float f32x4 __attribute__((ext_vector_type(4)));
typedef unsigned short ushort4v __attribute__((ext_vector_type(4)));
typedef _Float16 h2v __attribute__((ext_vector_type(2)));

__device__ __forceinline__ unsigned short f2bf(float f) {
  unsigned int u = __builtin_bit_cast(unsigned int, f);
  u += 0x7FFFu + ((u >> 16) & 1u);   // round-to-nearest-even
  return (unsigned short)(u >> 16);
}
__device__ __forceinline__ float h2f(unsigned short u) {
  return (float)__builtin_bit_cast(_Float16, u);
}

// packed f16x2 atomic add (global_atomic_pk_add_f16)
__device__ __forceinline__ void pk_atomic_add_f16(unsigned short* addr, float lo, float hi) {
  h2v v = { (_Float16)lo, (_Float16)hi };
#if __has_builtin(__builtin_amdgcn_global_atomic_fadd_v2f16)
  typedef h2v __attribute__((address_space(1))) *h2p;
  __builtin_amdgcn_global_atomic_fadd_v2f16((h2p)(unsigned long long)addr, v);
#elif __has_builtin(__builtin_amdgcn_flat_atomic_fadd_v2f16)
  __builtin_amdgcn_flat_atomic_fadd_v2f16((h2v*)addr, v);
#else
  unsafeAtomicAdd((__half2*)addr, *(__half2*)&v);
#endif
}

// ---- cast x (f32 -> bf16) ----
__global__ __launch_bounds__(256) void cast_x_kernel(const float* __restrict__ in,
                                                     unsigned short* __restrict__ out, int nvec) {
  int stride = gridDim.x * blockDim.x;
  for (int i = blockIdx.x * blockDim.x + threadIdx.x; i < nvec; i += stride) {
    float4 v = ((const float4*)in)[i];
    ushort4v o = { f2bf(v.x), f2bf(v.y), f2bf(v.z), f2bf(v.w) };
    ((ushort4v*)out)[i] = o;
  }
}

// ---- w [K][Cin][Cout] f32 -> wT [K][Cout][Cin] bf16 ----
__global__ __launch_bounds__(256) void wcast_kernel(const float* __restrict__ w,
                                                    unsigned short* __restrict__ wT, int total) {
  int i = blockIdx.x * blockDim.x + threadIdx.x;
  if (i >= total) return;
  int k = i >> 14, rem = i & 16383;
  int d = rem >> 7, c = rem & 127;
  wT[i] = f2bf(w[(k << 14) + (c << 7) + d]);
}

// ---- sparse conv, LDS-free: per-lane global gather -> MFMA -> pk-f16 scatter ----
// grid: (ceil(M/128), K), 256 threads (4 waves), no __syncthreads.
// A-frags: per-lane 16B loads from xb (L2/L3-resident). B-frags: per-lane 16B
// loads from wT (L2-resident, 864 KB total). Index loads hoisted to the top so
// gather/compute covers their latency; occupancy (no LDS, <=128 VGPR) covers
// the trailing atomic burst.
__global__ __launch_bounds__(256, 4) void spconv_direct(
    const unsigned short* __restrict__ xb, const unsigned short* __restrict__ wT,
    const int* __restrict__ iin, const int* __restrict__ iout,
    unsigned short* __restrict__ out, int M)
{
  const int k = blockIdx.y;
  const int r0 = blockIdx.x * 128;
  const int t = threadIdx.x;
  const int wv = t >> 6, l = t & 63;
  const int lrow = l & 15, lg = l >> 4;

  // A-row input indices (2 rows/lane)
  unsigned int rin[2];
  #pragma unroll
  for (int rt = 0; rt < 2; ++rt) {
    int r = r0 + wv * 32 + rt * 16 + lrow;
    rin[rt] = (r < M) ? (unsigned int)iin[k * M + r] : 0u;
  }
  // output rows this lane scatters (C layout: row = lg*4+i, col = lrow)
  int orow[2][4];
  #pragma unroll
  for (int rt = 0; rt < 2; ++rt)
    #pragma unroll
    for (int i = 0; i < 4; ++i) {
      int r = r0 + wv * 32 + rt * 16 + lg * 4 + i;
      orow[rt][i] = (r < M) ? iout[k * M + r] : -1;
    }

  const unsigned short* wk = wT + ((size_t)k << 14);

  f32x4 acc[2][8];
  #pragma unroll
  for (int a = 0; a < 2; ++a)
    #pragma unroll
    for (int b = 0; b < 8; ++b)
      acc[a][b] = (f32x4){0.f, 0.f, 0.f, 0.f};

  #pragma unroll
  for (int kk = 0; kk < 4; ++kk) {
    bf16x8 af[2];
    #pragma unroll
    for (int rt = 0; rt < 2; ++rt)
      af[rt] = *(const bf16x8*)(xb + ((size_t)rin[rt] << 7) + kk * 32 + lg * 8);
    #pragma unroll
    for (int ct = 0; ct < 8; ++ct) {
      int crow = ct * 16 + lrow;
      bf16x8 bfr = *(const bf16x8*)(wk + crow * 128 + kk * 32 + lg * 8);
      acc[0][ct] = __builtin_amdgcn_mfma_f32_16x16x32_bf16(af[0], bfr, acc[0][ct], 0, 0, 0);
      acc[1][ct] = __builtin_amdgcn_mfma_f32_16x16x32_bf16(af[1], bfr, acc[1][ct], 0, 0, 0);
    }
  }

  // scatter: adjacent channels live in adjacent lanes -> pair via shfl_xor(1),
  // one packed f16x2 atomic per channel pair. Even lanes ct 0-3, odd ct 4-7.
  const int colbase = (lrow & ~1);
  const bool evenlane = ((lrow & 1) == 0);
  #pragma unroll
  for (int rt = 0; rt < 2; ++rt) {
    #pragma unroll
    for (int i = 0; i < 4; ++i) {
      int or_ = orow[rt][i];
      unsigned short* dst = out + ((size_t)(or_ < 0 ? 0 : or_) << 7);
      #pragma unroll
      for (int ct = 0; ct < 8; ++ct) {
        float own = acc[rt][ct][i];
        float oth = __shfl_xor(own, 1, 64);      // all lanes participate
        bool mine = (evenlane == (ct < 4));
        if (or_ >= 0 && mine) {
          float lo = evenlane ? own : oth;
          float hi = evenlane ? oth : own;
          pk_atomic_add_f16(dst + ct * 16 + colbase, lo, hi);
        }
      }
    }
  }
}

// ---- BN stats: per-channel sum and sumsq over fp16 accumulator ----
__global__ __launch_bounds__(256) void bn_stats_kernel(const unsigned short* __restrict__ in,
                                                       float* __restrict__ st, int N) {
  int c = threadIdx.x & 127;
  int rh = threadIdx.x >> 7;
  float s = 0.f, s2 = 0.f;
  for (int r = blockIdx.x * 2 + rh; r < N; r += gridDim.x * 2) {
    float v = h2f(in[((size_t)r << 7) + c]);
    s += v; s2 += v * v;
  }
  atomicAdd(&st[c], s);
  atomicAdd(&st[128 + c], s2);
}

// ---- BN + ReLU -> bf16 (input to conv2) ----
__global__ __launch_bounds__(256) void bn_relu_bf16_kernel(const unsigned short* __restrict__ in,
    const float* __restrict__ st, const float* __restrict__ gamma, const float* __restrict__ beta,
    unsigned short* __restrict__ out, int nvec, float invN)
{
  int stride = gridDim.x * blockDim.x;
  for (int i = blockIdx.x * blockDim.x + threadIdx.x; i < nvec; i += stride) {
    int cb = (i & 31) * 4;
    ushort4v u = ((const ushort4v*)in)[i];
    ushort4v o;
    #pragma unroll
    for (int j = 0; j < 4; ++j) {
      int c = cb + j;
      float mean = st[c] * invN;
      float var = st[128 + c] * invN - mean * mean;
      float y = (h2f(u[j]) - mean) * rsqrtf(var + 1e-5f) * gamma[c] + beta[c];
      o[j] = f2bf(fmaxf(y, 0.f));
    }
    ((ushort4v*)out)[i] = o;
  }
}

// ---- BN + residual + ReLU -> f32 output ----
__global__ __launch_bounds__(256) void bn_add_relu_kernel(const unsigned short* __restrict__ in,
    const float* __restrict__ st, const float* __restrict__ gamma, const float* __restrict__ beta,
    const float* __restrict__ resid, float* __restrict__ out, int nvec, float invN)
{
  int stride = gridDim.x * blockDim.x;
  for (int i = blockIdx.x * blockDim.x + threadIdx.x; i < nvec; i += stride) {
    int cb = (i & 31) * 4;
    ushort4v u = ((const ushort4v*)in)[i];
    float4 rz = ((const float4*)resid)[i];
    float rr[4] = {rz.x, rz.y, rz.z, rz.w};
    float ov[4];
    #pragma unroll
    for (int j = 0; j < 4; ++j) {
      int c = cb + j;
      float mean = st[c] * invN;
      float var = st[128 + c] * invN - mean * mean;
      float y = (h2f(u[j]) - mean) * rsqrtf(var + 1e-5f) * gamma[c] + beta[c] + rr[j];
      ov[j] = fmaxf(y, 0.f);
    }
    float4 o; o.x = ov[0]; o.y = ov[1]; o.z = ov[2]; o.w = ov[3];
    ((float4*)out)[i] = o;
  }
}

extern "C" void kernel_launch(void* const* d_in, const int* in_sizes, int n_in,
                              void* d_out, int out_size, void* d_ws, size_t ws_size,
                              hipStream_t stream) {
  const float* x  = (const float*)d_in[0];
  const float* w1 = (const float*)d_in[1];
  const float* g1 = (const float*)d_in[2];
  const float* b1 = (const float*)d_in[3];
  const float* w2 = (const float*)d_in[4];
  const float* g2 = (const float*)d_in[5];
  const float* b2 = (const float*)d_in[6];
  const int* iin  = (const int*)d_in[7];
  const int* iout = (const int*)d_in[8];

  const int C = 128;
  const int N = in_sizes[0] / C;          // 100000
  const int K = in_sizes[1] / (C * C);    // 27
  const int M = in_sizes[7] / K;          // 50000
  const size_t nc = (size_t)N * C;
  const int wtot = K * C * C;
  const int nvec = (int)(nc / 4);
  const float invN = 1.0f / (float)N;

  // ---- workspace layout (~53 MB) ----
  size_t off = 0;
  auto alloc = [&](size_t bytes) { size_t o = off; off = (off + bytes + 255) & ~255ULL; return o; };
  char* ws = (char*)d_ws;
  size_t o_xb    = alloc(nc * 2);              // bf16 conv input
  size_t o_w1T   = alloc((size_t)wtot * 2);
  size_t o_w2T   = alloc((size_t)wtot * 2);
  size_t o_acc   = alloc(nc * 2);              // fp16 accumulator
  size_t o_stats = alloc(512 * 4);

  unsigned short* xb   = (unsigned short*)(ws + o_xb);
  unsigned short* w1T  = (unsigned short*)(ws + o_w1T);
  unsigned short* w2T  = (unsigned short*)(ws + o_w2T);
  unsigned short* accH = (unsigned short*)(ws + o_acc);
  float* stats         = (float*)(ws + o_stats);

  cast_x_kernel<<<2048, 256, 0, stream>>>(x, xb, nvec);
  wcast_kernel<<<(wtot + 255) / 256, 256, 0, stream>>>(w1, w1T, wtot);
  wcast_kernel<<<(wtot + 255) / 256, 256, 0, stream>>>(w2, w2T, wtot);
  hipMemsetAsync(stats, 0, 512 * 4, stream);
  hipMemsetAsync(accH, 0, nc * 2, stream);     // fp16 +0.0

  dim3 cgrid((M + 127) / 128, K);
  // conv1 -> accH (fp16, packed atomics)
  spconv_direct<<<cgrid, 256, 0, stream>>>(xb, w1T, iin, iout, accH, M);
  bn_stats_kernel<<<512, 256, 0, stream>>>(accH, stats, N);
  bn_relu_bf16_kernel<<<2048, 256, 0, stream>>>(accH, stats, g1, b1, xb, nvec, invN);
  // conv2 -> accH (re-zeroed)
  hipMemsetAsync(accH, 0, nc * 2, stream);
  spconv_direct<<<cgrid, 256, 0, stream>>>(xb, w2T, iin, iout, accH, M);
  bn_stats_kernel<<<512, 256, 0, stream>>>(accH, stats + 256, N);
  bn_add_relu_kernel<<<2048, 256, 0, stream>>>(accH, stats + 256, g2, b2, x, (float*)d_out, nvec, invN);
}

// Round 6
// 1032.020 us; speedup vs baseline: 1.4112x; 1.4112x over previous
//
#include <hip/hip_runtime.h>
#include <hip/hip_fp16.h>

typedef __bf16 bf16x8 __attribute__((ext_vector_type(8)));
typedef float f32x4 __attribute__((ext_vector_type(4)));
typedef unsigned short ushort4v __attribute__((ext_vector_type(4)));
typedef _Float16 h2v __attribute__((ext_vector_type(2)));

__device__ __forceinline__ unsigned short f2bf(float f) {
  unsigned int u = __builtin_bit_cast(unsigned int, f);
  u += 0x7FFFu + ((u >> 16) & 1u);   // round-to-nearest-even
  return (unsigned short)(u >> 16);
}
__device__ __forceinline__ float h2f(unsigned short u) {
  return (float)__builtin_bit_cast(_Float16, u);
}

// packed f16x2 atomic add of a pre-packed u32
__device__ __forceinline__ void pk_atomic_add_u32(unsigned short* addr, unsigned int packed) {
  h2v v = __builtin_bit_cast(h2v, packed);
#if __has_builtin(__builtin_amdgcn_global_atomic_fadd_v2f16)
  typedef h2v __attribute__((address_space(1))) *h2p;
  __builtin_amdgcn_global_atomic_fadd_v2f16((h2p)(unsigned long long)addr, v);
#elif __has_builtin(__builtin_amdgcn_flat_atomic_fadd_v2f16)
  __builtin_amdgcn_flat_atomic_fadd_v2f16((h2v*)addr, v);
#else
  unsafeAtomicAdd((__half2*)addr, *(__half2*)&v);
#endif
}

// ---- cast x (f32 -> bf16) ----
__global__ __launch_bounds__(256) void cast_x_kernel(const float* __restrict__ in,
                                                     unsigned short* __restrict__ out, int nvec) {
  int stride = gridDim.x * blockDim.x;
  for (int i = blockIdx.x * blockDim.x + threadIdx.x; i < nvec; i += stride) {
    float4 v = ((const float4*)in)[i];
    ushort4v o = { f2bf(v.x), f2bf(v.y), f2bf(v.z), f2bf(v.w) };
    ((ushort4v*)out)[i] = o;
  }
}

// ---- w [K][Cin][Cout] f32 -> wT [K][Cout][Cin] bf16 ----
__global__ __launch_bounds__(256) void wcast_kernel(const float* __restrict__ w,
                                                    unsigned short* __restrict__ wT, int total) {
  int i = blockIdx.x * blockDim.x + threadIdx.x;
  if (i >= total) return;
  int k = i >> 14, rem = i & 16383;
  int d = rem >> 7, c = rem & 127;
  wT[i] = f2bf(w[(k << 14) + (c << 7) + d]);
}

// ---- sparse conv: direct global gather -> MFMA -> LDS transpose ->
//      one full-row packed-f16 atomic burst per wave-instruction ----
// grid: (ceil(M/128), K), 256 threads (4 waves). LDS 32KB (f16x2-packed tile).
__global__ __launch_bounds__(256, 4) void spconv_rowsc(
    const unsigned short* __restrict__ xb, const unsigned short* __restrict__ wT,
    const int* __restrict__ iin, const int* __restrict__ iout,
    unsigned short* __restrict__ out, int M)
{
  __shared__ unsigned int accs[128 * 64];   // [row][64] u32 = 2 f16 channels, skewed
  const int k = blockIdx.y;
  const int r0 = blockIdx.x * 128;
  const int t = threadIdx.x;
  const int wv = t >> 6, l = t & 63;
  const int lrow = l & 15, lg = l >> 4;

  // A-row input indices (2 rows/lane)
  unsigned int rin[2];
  #pragma unroll
  for (int rt = 0; rt < 2; ++rt) {
    int r = r0 + wv * 32 + rt * 16 + lrow;
    rin[rt] = (r < M) ? (unsigned int)iin[k * M + r] : 0u;
  }

  const unsigned short* wk = wT + ((size_t)k << 14);

  f32x4 acc[2][8];
  #pragma unroll
  for (int a = 0; a < 2; ++a)
    #pragma unroll
    for (int b = 0; b < 8; ++b)
      acc[a][b] = (f32x4){0.f, 0.f, 0.f, 0.f};

  #pragma unroll
  for (int kk = 0; kk < 4; ++kk) {
    bf16x8 af[2];
    #pragma unroll
    for (int rt = 0; rt < 2; ++rt)
      af[rt] = *(const bf16x8*)(xb + ((size_t)rin[rt] << 7) + kk * 32 + lg * 8);
    #pragma unroll
    for (int ct = 0; ct < 8; ++ct) {
      int crow = ct * 16 + lrow;
      bf16x8 bfr = *(const bf16x8*)(wk + crow * 128 + kk * 32 + lg * 8);
      acc[0][ct] = __builtin_amdgcn_mfma_f32_16x16x32_bf16(af[0], bfr, acc[0][ct], 0, 0, 0);
      acc[1][ct] = __builtin_amdgcn_mfma_f32_16x16x32_bf16(af[1], bfr, acc[1][ct], 0, 0, 0);
    }
  }

  // pack accumulators into LDS tile: row-major, u32 = channels (2j, 2j+1),
  // skewed col = (col + row*8) & 63 -> 2-way bank conflicts max (free).
  // C layout: channel = ct*16 + (l&15), row = wv*32 + rt*16 + lg*4 + i.
  const bool evenlane = ((l & 1) == 0);
  #pragma unroll
  for (int rt = 0; rt < 2; ++rt)
    #pragma unroll
    for (int i = 0; i < 4; ++i) {
      int prow = wv * 32 + rt * 16 + lg * 4 + i;
      #pragma unroll
      for (int ct = 0; ct < 8; ++ct) {
        float own = acc[rt][ct][i];
        float oth = __shfl_xor(own, 1, 64);   // all lanes participate
        if (evenlane) {
          h2v hv = { (_Float16)own, (_Float16)oth };
          int col = ct * 8 + (lrow >> 1);
          accs[prow * 64 + ((col + prow * 8) & 63)] = __builtin_bit_cast(unsigned int, hv);
        }
      }
    }
  __syncthreads();

  // scatter: wave wv handles rows [wv*32, wv*32+32); one atomic instruction
  // per row = 64 lanes x pk_add covering the full 256B fp16 row.
  int rr = r0 + wv * 32 + (l & 31);
  int rid = (rr < M) ? iout[k * M + rr] : -1;
  for (int j = 0; j < 32; ++j) {
    int target = __shfl(rid, j, 64);
    int r = wv * 32 + j;
    if (target >= 0) {
      unsigned int val = accs[r * 64 + ((l + r * 8) & 63)];
      pk_atomic_add_u32(out + ((size_t)target << 7) + l * 2, val);
    }
  }
}

// ---- BN stats: per-channel sum and sumsq over fp16 accumulator ----
__global__ __launch_bounds__(256) void bn_stats_kernel(const unsigned short* __restrict__ in,
                                                       float* __restrict__ st, int N) {
  int c = threadIdx.x & 127;
  int rh = threadIdx.x >> 7;
  float s = 0.f, s2 = 0.f;
  for (int r = blockIdx.x * 2 + rh; r < N; r += gridDim.x * 2) {
    float v = h2f(in[((size_t)r << 7) + c]);
    s += v; s2 += v * v;
  }
  atomicAdd(&st[c], s);
  atomicAdd(&st[128 + c], s2);
}

// ---- BN + ReLU -> bf16 (input to conv2) ----
__global__ __launch_bounds__(256) void bn_relu_bf16_kernel(const unsigned short* __restrict__ in,
    const float* __restrict__ st, const float* __restrict__ gamma, const float* __restrict__ beta,
    unsigned short* __restrict__ out, int nvec, float invN)
{
  int stride = gridDim.x * blockDim.x;
  for (int i = blockIdx.x * blockDim.x + threadIdx.x; i < nvec; i += stride) {
    int cb = (i & 31) * 4;
    ushort4v u = ((const ushort4v*)in)[i];
    ushort4v o;
    #pragma unroll
    for (int j = 0; j < 4; ++j) {
      int c = cb + j;
      float mean = st[c] * invN;
      float var = st[128 + c] * invN - mean * mean;
      float y = (h2f(u[j]) - mean) * rsqrtf(var + 1e-5f) * gamma[c] + beta[c];
      o[j] = f2bf(fmaxf(y, 0.f));
    }
    ((ushort4v*)out)[i] = o;
  }
}

// ---- BN + residual + ReLU -> f32 output ----
__global__ __launch_bounds__(256) void bn_add_relu_kernel(const unsigned short* __restrict__ in,
    const float* __restrict__ st, const float* __restrict__ gamma, const float* __restrict__ beta,
    const float* __restrict__ resid, float* __restrict__ out, int nvec, float invN)
{
  int stride = gridDim.x * blockDim.x;
  for (int i = blockIdx.x * blockDim.x + threadIdx.x; i < nvec; i += stride) {
    int cb = (i & 31) * 4;
    ushort4v u = ((const ushort4v*)in)[i];
    float4 rz = ((const float4*)resid)[i];
    float rr[4] = {rz.x, rz.y, rz.z, rz.w};
    float ov[4];
    #pragma unroll
    for (int j = 0; j < 4; ++j) {
      int c = cb + j;
      float mean = st[c] * invN;
      float var = st[128 + c] * invN - mean * mean;
      float y = (h2f(u[j]) - mean) * rsqrtf(var + 1e-5f) * gamma[c] + beta[c] + rr[j];
      ov[j] = fmaxf(y, 0.f);
    }
    float4 o; o.x = ov[0]; o.y = ov[1]; o.z = ov[2]; o.w = ov[3];
    ((float4*)out)[i] = o;
  }
}

extern "C" void kernel_launch(void* const* d_in, const int* in_sizes, int n_in,
                              void* d_out, int out_size, void* d_ws, size_t ws_size,
                              hipStream_t stream) {
  const float* x  = (const float*)d_in[0];
  const float* w1 = (const float*)d_in[1];
  const float* g1 = (const float*)d_in[2];
  const float* b1 = (const float*)d_in[3];
  const float* w2 = (const float*)d_in[4];
  const float* g2 = (const float*)d_in[5];
  const float* b2 = (const float*)d_in[6];
  const int* iin  = (const int*)d_in[7];
  const int* iout = (const int*)d_in[8];

  const int C = 128;
  const int N = in_sizes[0] / C;          // 100000
  const int K = in_sizes[1] / (C * C);    // 27
  const int M = in_sizes[7] / K;          // 50000
  const size_t nc = (size_t)N * C;
  const int wtot = K * C * C;
  const int nvec = (int)(nc / 4);
  const float invN = 1.0f / (float)N;

  // ---- workspace layout (~53 MB) ----
  size_t off = 0;
  auto alloc = [&](size_t bytes) { size_t o = off; off = (off + bytes + 255) & ~255ULL; return o; };
  char* ws = (char*)d_ws;
  size_t o_xb    = alloc(nc * 2);              // bf16 conv input
  size_t o_w1T   = alloc((size_t)wtot * 2);
  size_t o_w2T   = alloc((size_t)wtot * 2);
  size_t o_acc   = alloc(nc * 2);              // fp16 accumulator
  size_t o_stats = alloc(512 * 4);

  unsigned short* xb   = (unsigned short*)(ws + o_xb);
  unsigned short* w1T  = (unsigned short*)(ws + o_w1T);
  unsigned short* w2T  = (unsigned short*)(ws + o_w2T);
  unsigned short* accH = (unsigned short*)(ws + o_acc);
  float* stats         = (float*)(ws + o_stats);

  cast_x_kernel<<<2048, 256, 0, stream>>>(x, xb, nvec);
  wcast_kernel<<<(wtot + 255) / 256, 256, 0, stream>>>(w1, w1T, wtot);
  wcast_kernel<<<(wtot + 255) / 256, 256, 0, stream>>>(w2, w2T, wtot);
  hipMemsetAsync(stats, 0, 512 * 4, stream);
  hipMemsetAsync(accH, 0, nc * 2, stream);     // fp16 +0.0

  dim3 cgrid((M + 127) / 128, K);
  // conv1 -> accH (fp16, row-burst packed atomics)
  spconv_rowsc<<<cgrid, 256, 0, stream>>>(xb, w1T, iin, iout, accH, M);
  bn_stats_kernel<<<512, 256, 0, stream>>>(accH, stats, N);
  bn_relu_bf16_kernel<<<2048, 256, 0, stream>>>(accH, stats, g1, b1, xb, nvec, invN);
  // conv2 -> accH (re-zeroed)
  hipMemsetAsync(accH, 0, nc * 2, stream);
  spconv_rowsc<<<cgrid, 256, 0, stream>>>(xb, w2T, iin, iout, accH, M);
  bn_stats_kernel<<<512, 256, 0, stream>>>(accH, stats + 256, N);
  bn_add_relu_kernel<<<2048, 256, 0, stream>>>(accH, stats + 256, g2, b2, x, (float*)d_out, nvec, invN);
}